// Round 10
// baseline (154.746 us; speedup 1.0000x reference)
//
#include <hip/hip_runtime.h>

// MultiHashEncoding: 2-level dense grid trilinear interpolation.
// r7-r9 evidence: sorted gather kernel pinned at ~85-98us with ~150 lines in
// flight per CU regardless of structure (L2-hit latency bound; compiler caps
// per-thread MLP). r10: bin-cooperative LDS staging — one block per spatial
// bin stages the bin's emb sub-volumes to LDS once, points then gather from
// LDS (throughput-bound, ~12cy/read) instead of L2 (~580cy latency).
//
// Reference semantics (bit-exact corners): corner = floor(coords + OFFSET)
// with f32 add BEFORE floor; clip to [0,dim-1]; weight from CLIPPED corner.
//
// Staged-extent proof sketch (why corners always hit the staged LDS tile):
//   key uses ix=(int)(px*15), iy=(int)(py*135), iz=(int)(pz*240) — the SAME
//   f32 products as cx,cy,cz, so floor(cx) in [2bx,2bx+1], floor(cy) in
//   [8by,8by+7], floor(cz) in [8bz,8bz+7]. corner = floor(c+1.0f) <=
//   floor(c)+2 (binade rounding). Level0 extents: x 4, y 10, z 10. Level1:
//   c1z = cz/2 exactly (exponent-only) -> floor in [4bz,4bz+3] -> z extent 6;
//   c1x in [1.0667bx, 1.0667(bx+1)) -> x1b=bx, extent 4; c1y in
//   [4.0296by, +4.03) -> y1b=(544*by)/135, extent 8. All include the +2 case.

typedef float floatx4 __attribute__((ext_vector_type(4)));

#define KXB 8
#define KYB 17
#define KZB 31
#define NBINS (KXB * KYB * KZB)          // 4216
#define SCAN_T 256
#define CHUNK ((NBINS + SCAN_T - 1) / SCAN_T)  // 17

// LDS tile geometry; cell stride 20 dwords (80B) spreads bank bases over all
// 8 mod-32/4 classes -> ~2-way conflicts (free, m136).
#define L0X 4
#define L0Y 10
#define L0Z 10
#define L0CELLS (L0X * L0Y * L0Z)        // 400
#define L1X 4
#define L1Y 8
#define L1Z 6
#define L1CELLS (L1X * L1Y * L1Z)        // 192
#define CSTR 20

__device__ __forceinline__ int point_key(float px, float py, float pz) {
    int ix = (int)(px * 15.0f);  ix = min(max(ix, 0), 15);
    int iy = (int)(py * 135.0f); iy = min(max(iy, 0), 135);
    int iz = (int)(pz * 240.0f); iz = min(max(iz, 0), 240);
    return ((ix >> 1) * KYB + (iy >> 3)) * KZB + (iz >> 3);
}

__device__ __forceinline__ void load4pts(const float* __restrict__ pts, int i4,
                                         float px[4], float py[4], float pz[4]) {
    const floatx4* v = (const floatx4*)(pts + (size_t)i4 * 3);
    const floatx4 a = v[0], b = v[1], c = v[2];
    px[0] = a.x; py[0] = a.y; pz[0] = a.z;
    px[1] = a.w; py[1] = b.x; pz[1] = b.y;
    px[2] = b.z; py[2] = b.w; pz[2] = c.x;
    px[3] = c.y; py[3] = c.z; pz[3] = c.w;
}

// ---------------- pass 1: packed key<<19|rank (one atomic) ----------------
__global__ __launch_bounds__(256)
void k_hist(const float* __restrict__ pts, int n,
            unsigned* __restrict__ packed, unsigned* __restrict__ hist) {
    const int i4 = (blockIdx.x * blockDim.x + threadIdx.x) * 4;
    if (i4 >= n) return;
    if (i4 + 3 < n) {
        float px[4], py[4], pz[4];
        load4pts(pts, i4, px, py, pz);
        unsigned pk[4];
#pragma unroll
        for (int j = 0; j < 4; ++j) {
            const unsigned k = (unsigned)point_key(px[j], py[j], pz[j]);
            const unsigned r = atomicAdd(&hist[k], 1u);
            pk[j] = (k << 19) | r;      // rank < 2^19 guaranteed (uniform pts)
        }
        *(uint4*)(packed + i4) = make_uint4(pk[0], pk[1], pk[2], pk[3]);
    } else {
        for (int j = 0; j < 4 && i4 + j < n; ++j) {
            const size_t b = (size_t)(i4 + j) * 3;
            const unsigned k = (unsigned)point_key(pts[b], pts[b+1], pts[b+2]);
            packed[i4 + j] = (k << 19) | atomicAdd(&hist[k], 1u);
        }
    }
}

// ---------------- pass 2: exclusive scan (one block), base[NBINS]=n --------
__global__ __launch_bounds__(SCAN_T)
void k_scan(const unsigned* __restrict__ hist, unsigned* __restrict__ base) {
    __shared__ unsigned part[SCAN_T];
    const int t = threadIdx.x;
    unsigned local[CHUNK];
    unsigned s = 0;
#pragma unroll
    for (int j = 0; j < CHUNK; ++j) {
        const int idx = t * CHUNK + j;
        const unsigned v = (idx < NBINS) ? hist[idx] : 0u;
        local[j] = s;
        s += v;
    }
    part[t] = s;
    __syncthreads();
    for (int off = 1; off < SCAN_T; off <<= 1) {
        unsigned y = 0;
        if (t >= off) y = part[t - off];
        __syncthreads();
        if (t >= off) part[t] += y;
        __syncthreads();
    }
    const unsigned b = part[t] - s;
#pragma unroll
    for (int j = 0; j < CHUNK; ++j) {
        const int idx = t * CHUNK + j;
        if (idx < NBINS) base[idx] = b + local[j];
    }
    if (t == SCAN_T - 1) base[NBINS] = part[t];
}

// ---------------- pass 3: atomic-free scatter ----------------
__global__ __launch_bounds__(256)
void k_scatter(const float* __restrict__ pts, int n,
               const unsigned* __restrict__ packed,
               const unsigned* __restrict__ base, floatx4* __restrict__ sorted) {
    const int i4 = (blockIdx.x * blockDim.x + threadIdx.x) * 4;
    if (i4 >= n) return;
    if (i4 + 3 < n) {
        float px[4], py[4], pz[4];
        load4pts(pts, i4, px, py, pz);
        const uint4 pk = *(const uint4*)(packed + i4);
        const unsigned pp[4] = { pk.x, pk.y, pk.z, pk.w };
#pragma unroll
        for (int j = 0; j < 4; ++j) {
            const unsigned pos = base[pp[j] >> 19] + (pp[j] & 0x7FFFFu);
            floatx4 rec = { px[j], py[j], pz[j], __int_as_float(i4 + j) };
            sorted[pos] = rec;
        }
    } else {
        for (int j = 0; j < 4 && i4 + j < n; ++j) {
            const size_t b = (size_t)(i4 + j) * 3;
            const unsigned pk = packed[i4 + j];
            const unsigned pos = base[pk >> 19] + (pk & 0x7FFFFu);
            floatx4 rec = { pts[b], pts[b+1], pts[b+2], __int_as_float(i4 + j) };
            sorted[pos] = rec;
        }
    }
}

// ---------------- per-level corner setup (LDS dword offsets) ----------------
__device__ __forceinline__ void setup_lds(float cx, float cy, float cz,
                                          float tm1, float hm1, float wm1,
                                          int xb, int yb, int zb,
                                          int sx, int sy, int d,
                                          int* __restrict__ off,
                                          float* __restrict__ w) {
    float gx[2] = { floorf(cx), floorf(cx + 1.0f) };
    float gy[2] = { floorf(cy), floorf(cy + 1.0f) };
    float gz[2] = { floorf(cz), floorf(cz + 1.0f) };
    float wx[2], wy[2], wz[2];
    int   xo[2], yo[2], zo[2];
#pragma unroll
    for (int b = 0; b < 2; ++b) {
        gx[b] = fminf(fmaxf(gx[b], 0.0f), tm1);
        gy[b] = fminf(fmaxf(gy[b], 0.0f), hm1);
        gz[b] = fminf(fmaxf(gz[b], 0.0f), wm1);
        wx[b] = 1.0f - fabsf(gx[b] - cx);
        wy[b] = 1.0f - fabsf(gy[b] - cy);
        wz[b] = 1.0f - fabsf(gz[b] - cz);
        xo[b] = ((int)gx[b] - xb) * sx;
        yo[b] = ((int)gy[b] - yb) * sy;
        zo[b] = ((int)gz[b] - zb) * CSTR + d;
    }
    float wyz[4];
    int   yzo[4];
#pragma unroll
    for (int j = 0; j < 2; ++j)
#pragma unroll
        for (int k = 0; k < 2; ++k) {
            wyz[2 * j + k] = wy[j] * wz[k];
            yzo[2 * j + k] = yo[j] + zo[k];
        }
#pragma unroll
    for (int c = 0; c < 8; ++c) {
        const int i = (c >> 2) & 1, jk = c & 3;
        w[c]   = wx[i] * wyz[jk];
        off[c] = xo[i] + yzo[jk];
    }
}

// ---------------- main: one block per bin, LDS-staged gathers ----------------
__global__ __launch_bounds__(256)
void k_main_bins(const floatx4* __restrict__ sorted,
                 const unsigned* __restrict__ base,
                 const float* __restrict__ emb0,
                 const float* __restrict__ emb1,
                 float* __restrict__ out) {
    // bijective XCD swizzle: 4216 = 8 * 527 exactly
    const int bin = (blockIdx.x & 7) * 527 + (blockIdx.x >> 3);
    const unsigned pstart = base[bin], pend = base[bin + 1];
    if (pstart == pend) return;   // uniform: safe before barriers

    const int bz = bin % KZB;
    const int t1 = bin / KZB;
    const int by = t1 % KYB;
    const int bx = t1 / KYB;

    const int x0 = bx * 2, y0 = by * 8, z0 = bz * 8;
    const int x1b = bx, y1b = (544 * by) / 135, z1b = bz * 4;

    __shared__ float lds0[L0CELLS * CSTR];   // 32.0 KB
    __shared__ float lds1[L1CELLS * CSTR];   // 15.4 KB

    const int tid = threadIdx.x;
    for (int idx = tid; idx < L0CELLS * 4; idx += 256) {
        const int cell = idx >> 2, q = (idx & 3) * 4;
        const int lz = cell % L0Z;
        const int t = cell / L0Z;
        const int ly = t % L0Y, lx = t / L0Y;
        const int gx = min(x0 + lx, 15), gy = min(y0 + ly, 135), gz = min(z0 + lz, 240);
        const floatx4 v = *(const floatx4*)(emb0 + ((size_t)(gx * 136 + gy) * 241 + gz) * 16 + q);
        *(floatx4*)(lds0 + cell * CSTR + q) = v;
    }
    for (int idx = tid; idx < L1CELLS * 4; idx += 256) {
        const int cell = idx >> 2, q = (idx & 3) * 4;
        const int lz = cell % L1Z;
        const int t = cell / L1Z;
        const int ly = t % L1Y, lx = t / L1Y;
        const int gx = min(x1b + lx, 8), gy = min(y1b + ly, 68), gz = min(z1b + lz, 120);
        const floatx4 v = *(const floatx4*)(emb1 + ((size_t)(gx * 69 + gy) * 121 + gz) * 16 + q);
        *(floatx4*)(lds1 + cell * CSTR + q) = v;
    }
    __syncthreads();

    const int quad = tid >> 2;          // 64 quads/block
    const int d = (tid & 3) * 4;        // 4 dims per lane
    const unsigned cnt = pend - pstart;
    for (unsigned pp = quad; pp < cnt; pp += 64) {
        const floatx4 rec = sorted[pstart + pp];
        const int orig = __float_as_int(rec.w);
        int   o0[8], o1[8];
        float w0[8], w1[8];
        setup_lds(rec.x * 15.0f, rec.y * 135.0f, rec.z * 240.0f,
                  15.0f, 135.0f, 240.0f, x0, y0, z0,
                  L0Y * L0Z * CSTR, L0Z * CSTR, d, o0, w0);
        setup_lds(rec.x * 8.0f, rec.y * 68.0f, rec.z * 120.0f,
                  8.0f, 68.0f, 120.0f, x1b, y1b, z1b,
                  L1Y * L1Z * CSTR, L1Z * CSTR, d, o1, w1);

        floatx4 a0 = {0.f, 0.f, 0.f, 0.f}, a1 = {0.f, 0.f, 0.f, 0.f};
#pragma unroll
        for (int c = 0; c < 8; ++c) a0 += w0[c] * *(const floatx4*)(lds0 + o0[c]);
#pragma unroll
        for (int c = 0; c < 8; ++c) a1 += w1[c] * *(const floatx4*)(lds1 + o1[c]);

        float* row = out + (size_t)orig * 32 + d;
        __builtin_nontemporal_store(a0, (floatx4*)row);
        __builtin_nontemporal_store(a1, (floatx4*)(row + 16));
    }
}

// ---------------- fallback (no workspace): direct global gathers ------------
__device__ __forceinline__ void setup_glb(float cx, float cy, float cz,
                                          float tm1, float hm1, float wm1,
                                          int sh, int sw, int d,
                                          int* __restrict__ off,
                                          float* __restrict__ w) {
    float gx[2] = { floorf(cx), floorf(cx + 1.0f) };
    float gy[2] = { floorf(cy), floorf(cy + 1.0f) };
    float gz[2] = { floorf(cz), floorf(cz + 1.0f) };
    float wx[2], wy[2], wz[2];
    int   xo[2], yo[2], zo[2];
#pragma unroll
    for (int b = 0; b < 2; ++b) {
        gx[b] = fminf(fmaxf(gx[b], 0.0f), tm1);
        gy[b] = fminf(fmaxf(gy[b], 0.0f), hm1);
        gz[b] = fminf(fmaxf(gz[b], 0.0f), wm1);
        wx[b] = 1.0f - fabsf(gx[b] - cx);
        wy[b] = 1.0f - fabsf(gy[b] - cy);
        wz[b] = 1.0f - fabsf(gz[b] - cz);
        xo[b] = (int)gx[b] * sh;
        yo[b] = (int)gy[b] * sw;
        zo[b] = (int)gz[b] * 16 + d;
    }
#pragma unroll
    for (int c = 0; c < 8; ++c) {
        const int i = (c >> 2) & 1, j = (c >> 1) & 1, k = c & 1;
        w[c]   = wx[i] * (wy[j] * wz[k]);
        off[c] = xo[i] + yo[j] + zo[k];
    }
}

__global__ __launch_bounds__(256)
void k_main_plain(const float* __restrict__ pts,
                  const float* __restrict__ emb0,
                  const float* __restrict__ emb1,
                  float* __restrict__ out, int n) {
    const int g = blockIdx.x * blockDim.x + threadIdx.x;
    const int p = g >> 2;
    const int d = (g & 3) * 4;
    if (p >= n) return;
    const size_t b = (size_t)p * 3;
    const float px = pts[b], py = pts[b + 1], pz = pts[b + 2];
    int   o0[8], o1[8];
    float w0[8], w1[8];
    setup_glb(px * 15.0f, py * 135.0f, pz * 240.0f, 15.0f, 135.0f, 240.0f,
              136 * 241 * 16, 241 * 16, d, o0, w0);
    setup_glb(px * 8.0f, py * 68.0f, pz * 120.0f, 8.0f, 68.0f, 120.0f,
              69 * 121 * 16, 121 * 16, d, o1, w1);
    floatx4 a0 = {0.f, 0.f, 0.f, 0.f}, a1 = {0.f, 0.f, 0.f, 0.f};
#pragma unroll
    for (int c = 0; c < 8; ++c) a0 += w0[c] * *(const floatx4*)(emb0 + o0[c]);
#pragma unroll
    for (int c = 0; c < 8; ++c) a1 += w1[c] * *(const floatx4*)(emb1 + o1[c]);
    float* row = out + (size_t)p * 32 + d;
    __builtin_nontemporal_store(a0, (floatx4*)row);
    __builtin_nontemporal_store(a1, (floatx4*)(row + 16));
}

extern "C" void kernel_launch(void* const* d_in, const int* in_sizes, int n_in,
                              void* d_out, int out_size, void* d_ws, size_t ws_size,
                              hipStream_t stream) {
    const float* pts  = (const float*)d_in[0];
    const float* emb0 = (const float*)d_in[1];
    const float* emb1 = (const float*)d_in[2];
    float* out = (float*)d_out;
    const int n = in_sizes[0] / 3;

    const int block = 256;
    const int n4      = (n + 3) / 4;
    const int grid_p4 = (n4 + block - 1) / block;
    const int grid_4l = (int)(((long long)n * 4 + block - 1) / block);

    // workspace layout
    const size_t off_packed = 0;
    const size_t off_sorted = ((size_t)n * 4 + 15) & ~(size_t)15;
    const size_t off_hist   = off_sorted + (size_t)n * 16;
    const size_t off_base   = off_hist + (size_t)NBINS * 4;
    const size_t need       = off_base + (size_t)(NBINS + 1) * 4;

    if (ws_size < need) {
        k_main_plain<<<grid_4l, block, 0, stream>>>(pts, emb0, emb1, out, n);
        return;
    }

    char* ws = (char*)d_ws;
    unsigned* packed = (unsigned*)(ws + off_packed);
    floatx4*  sorted = (floatx4*)(ws + off_sorted);
    unsigned* hist   = (unsigned*)(ws + off_hist);
    unsigned* base   = (unsigned*)(ws + off_base);

    hipMemsetAsync(hist, 0, (size_t)NBINS * 4, stream);
    k_hist<<<grid_p4, block, 0, stream>>>(pts, n, packed, hist);
    k_scan<<<1, SCAN_T, 0, stream>>>(hist, base);
    k_scatter<<<grid_p4, block, 0, stream>>>(pts, n, packed, base, sorted);
    k_main_bins<<<NBINS, block, 0, stream>>>(sorted, base, emb0, emb1, out);
}